// Round 3
// baseline (307.604 us; speedup 1.0000x reference)
//
#include <hip/hip_runtime.h>

// ---- problem constants --------------------------------------------------
#define B_ 4
#define L_ 4096
#define D_ 256
#define M_ 512
#define C_ 256
#define NC_ 16
#define NG_ (B_*NC_)
#define EPS_ 1e-6f
#define RSQRT_D_ 0.0625f
#define RSQRT_M_ 0.044194173824159216f

typedef __attribute__((ext_vector_type(8))) short short8;
typedef __attribute__((ext_vector_type(4))) short short4v;
typedef __attribute__((ext_vector_type(4))) float floatx4;

// ---- bf16 helpers (RNE) -------------------------------------------------
__device__ __forceinline__ short f2b(float f) {
  union { float f; unsigned u; } c; c.f = f;
  unsigned r = c.u + 0x7fffu + ((c.u >> 16) & 1u);
  return (short)(r >> 16);
}
__device__ __forceinline__ float b2f(short s) {
  union { unsigned u; float f; } c; c.u = ((unsigned)(unsigned short)s) << 16;
  return c.f;
}

// ---- async 16B global->LDS (wave-uniform LDS base + lane*16) ------------
__device__ __forceinline__ void async_copy16(short* lds, const short* gp) {
  __builtin_amdgcn_global_load_lds(
      (const __attribute__((address_space(1))) unsigned int*)gp,
      (__attribute__((address_space(3))) unsigned int*)(unsigned int)(unsigned long long)lds,
      16, 0, 0);
}

// ---- workspace layout (byte offsets) ------------------------------------
#define OFF_S    0u                 // fp32 [64][256 d][512 m]; Wt aliases head
#define OFF_WT   0u                 // bf16 [512 n][256 k] (dead before chunkstate)
#define OFF_QP   33554432u          // bf16 [16384][512]
#define OFF_KP   50331648u          // bf16 [16384][512]
#define OFF_KPT  67108864u          // bf16 [64][512][256]
#define OFF_VT   83886080u          // bf16 [64][256][256]
#define OFF_AM   92274688u          // bf16 [64][256][256]
#define OFF_PB   100663296u         // bf16 [64][256][512]
#define OFF_Z    117440512u         // fp32 [64][512]
#define OFF_DEN  117571584u         // fp32 [16384]

// ======================================================================
// MFMA GEMM core, GLL staging: C[128x128] += A[128xK] * B[128xK]^T
// A,B row-major bf16 [row][k]. 256 threads = 4 waves (2x2). BK=64.
// LDS slot(m,c) = c*128 + (m^c); GLL lane l sources row m64*64+(l^c) so the
// lane-linear LDS placement lands in the swizzled layout. Fragment
// ds_read_b128: slot%8 = (ml^c)&7 -> 2 lanes per bank-quad per 16-group.
// ======================================================================
__device__ __forceinline__ void mfma_tile_gemm(
    const short* __restrict__ Ag, int lda,
    const short* __restrict__ Bg, int ldb,
    int K, short* sA, short* sB, floatx4 acc[4][4])
{
  const int tid  = threadIdx.x;
  const int lane = tid & 63;
  const int wave = tid >> 6;
  const int wm = wave >> 1, wn = wave & 1;
  const int q = lane >> 4, ml = lane & 15;

  for (int k0 = 0; k0 < K; k0 += 64) {
    #pragma unroll
    for (int n = 0; n < 4; ++n) {
      int idx = wave * 4 + n;            // 0..15
      int c = idx >> 1, m64 = idx & 1;
      int m = m64 * 64 + (lane ^ c);
      async_copy16(sA + (c * 128 + m64 * 64) * 8,
                   Ag + (size_t)m * lda + k0 + c * 8);
      async_copy16(sB + (c * 128 + m64 * 64) * 8,
                   Bg + (size_t)m * ldb + k0 + c * 8);
    }
    __syncthreads();
    #pragma unroll
    for (int ks = 0; ks < 2; ++ks) {
      short8 a[4], b[4];
      int c = ks * 4 + q;
      #pragma unroll
      for (int i = 0; i < 4; ++i) {
        int ra = (wm * 64 + i * 16 + ml) ^ c;
        a[i] = *(const short8*)(sA + (c * 128 + ra) * 8);
        int rb = (wn * 64 + i * 16 + ml) ^ c;
        b[i] = *(const short8*)(sB + (c * 128 + rb) * 8);
      }
      #pragma unroll
      for (int i = 0; i < 4; ++i)
        #pragma unroll
        for (int j = 0; j < 4; ++j)
          acc[i][j] = __builtin_amdgcn_mfma_f32_16x16x32_bf16(a[i], b[j], acc[i][j], 0, 0, 0);
    }
    __syncthreads();
  }
}

// ---- K1: generic fp32 [r][c] -> bf16 [c][r] tile transpose --------------
__global__ __launch_bounds__(256) void transpose_cvt_kernel(
    const float* __restrict__ in, short* __restrict__ out,
    int ld_in, int ld_out, long sg_in, long sg_out)
{
  __shared__ short sm[64 * 65];
  const int g = blockIdx.z;
  const int r0 = blockIdx.y * 64, c0 = blockIdx.x * 64;
  const float* src = in + (size_t)g * sg_in + (size_t)r0 * ld_in + c0;
  short* dst = out + (size_t)g * sg_out + (size_t)c0 * ld_out + r0;
  const int tid = threadIdx.x;
  #pragma unroll
  for (int it = 0; it < 4; ++it) {
    int ci = tid + 256 * it;
    int row = ci >> 4, c4 = ci & 15;
    float4 x = *(const float4*)(src + (size_t)row * ld_in + c4 * 4);
    sm[(c4 * 4 + 0) * 65 + row] = f2b(x.x);
    sm[(c4 * 4 + 1) * 65 + row] = f2b(x.y);
    sm[(c4 * 4 + 2) * 65 + row] = f2b(x.z);
    sm[(c4 * 4 + 3) * 65 + row] = f2b(x.w);
  }
  __syncthreads();
  #pragma unroll
  for (int it = 0; it < 2; ++it) {
    int ci = tid + 256 * it;
    int dr = ci >> 3, t8 = ci & 7;
    short8 o;
    #pragma unroll
    for (int u = 0; u < 8; ++u) o[u] = sm[dr * 65 + t8 * 8 + u];
    *(short8*)(dst + (size_t)dr * ld_out + t8 * 8) = o;
  }
}

// ---- K2/K3: phi = exp(X@W/sqrt(d) - 0.5||x||^2)/sqrt(M), fused cvt+ssq --
// A operand: fp32 global -> convert -> swizzled ds_write. B: GLL. In-kernel
// row ssq: per-thread partials over its 32 elems/row -> 8-lane shuffle -> LDS.
template<bool WRITE_T>
__global__ __launch_bounds__(256) void phi_mfma_kernel(
    const float* __restrict__ X, const short* __restrict__ Wt,
    short* __restrict__ outP, short* __restrict__ outT)
{
  __shared__ short smem[17664];   // sA 8192 | sB 8192 | tbuf overlaps | sqs @17408
  short* sA = smem;
  short* sB = smem + 8192;
  float* sqs = (float*)(smem + 17408);
  const int row0 = blockIdx.y * 128, col0 = blockIdx.x * 128;
  const int tid = threadIdx.x, lane = tid & 63, wave = tid >> 6;
  const int wm = wave >> 1, wn = wave & 1, q = lane >> 4, ml = lane & 15;
  floatx4 acc[4][4];
  #pragma unroll
  for (int i = 0; i < 4; ++i)
    #pragma unroll
    for (int j = 0; j < 4; ++j) acc[i][j] = (floatx4){0.f,0.f,0.f,0.f};

  float ssq[4] = {0.f, 0.f, 0.f, 0.f};
  for (int k0 = 0; k0 < D_; k0 += 64) {
    #pragma unroll
    for (int it = 0; it < 4; ++it) {
      int ci = tid + 256 * it;
      int m = ci >> 3, c = ci & 7;
      const float* src = X + (size_t)(row0 + m) * D_ + k0 + c * 8;
      float4 x0 = *(const float4*)src;
      float4 x1 = *(const float4*)(src + 4);
      short8 vv;
      vv[0] = f2b(x0.x); vv[1] = f2b(x0.y); vv[2] = f2b(x0.z); vv[3] = f2b(x0.w);
      vv[4] = f2b(x1.x); vv[5] = f2b(x1.y); vv[6] = f2b(x1.z); vv[7] = f2b(x1.w);
      ssq[it] += x0.x*x0.x + x0.y*x0.y + x0.z*x0.z + x0.w*x0.w
               + x1.x*x1.x + x1.y*x1.y + x1.z*x1.z + x1.w*x1.w;
      *(short8*)(sA + (c * 128 + (m ^ c)) * 8) = vv;
    }
    #pragma unroll
    for (int n = 0; n < 4; ++n) {
      int idx = wave * 4 + n;
      int c = idx >> 1, m64 = idx & 1;
      async_copy16(sB + (c * 128 + m64 * 64) * 8,
                   Wt + (size_t)(col0 + m64 * 64 + (lane ^ c)) * D_ + k0 + c * 8);
    }
    __syncthreads();
    #pragma unroll
    for (int ks = 0; ks < 2; ++ks) {
      short8 a[4], b[4];
      int c = ks * 4 + q;
      #pragma unroll
      for (int i = 0; i < 4; ++i) {
        int ra = (wm * 64 + i * 16 + ml) ^ c;
        a[i] = *(const short8*)(sA + (c * 128 + ra) * 8);
        int rb = (wn * 64 + i * 16 + ml) ^ c;
        b[i] = *(const short8*)(sB + (c * 128 + rb) * 8);
      }
      #pragma unroll
      for (int i = 0; i < 4; ++i)
        #pragma unroll
        for (int j = 0; j < 4; ++j)
          acc[i][j] = __builtin_amdgcn_mfma_f32_16x16x32_bf16(a[i], b[j], acc[i][j], 0, 0, 0);
    }
    __syncthreads();
  }
  // reduce ssq across the 8 threads sharing tid>>3 (consecutive lanes)
  #pragma unroll
  for (int o = 1; o < 8; o <<= 1)
    #pragma unroll
    for (int it = 0; it < 4; ++it) ssq[it] += __shfl_xor(ssq[it], o);
  if ((tid & 7) == 0) {
    #pragma unroll
    for (int it = 0; it < 4; ++it) sqs[(tid >> 3) + 32 * it] = 0.5f * ssq[it];
  }
  __syncthreads();
  // epilogue
  #pragma unroll
  for (int i = 0; i < 4; ++i) {
    int rl = wm * 64 + i * 16 + q * 4;
    float sqv[4];
    #pragma unroll
    for (int r = 0; r < 4; ++r) sqv[r] = sqs[rl + r];
    #pragma unroll
    for (int j = 0; j < 4; ++j) {
      int cl = wn * 64 + j * 16 + ml;
      short4v tb;
      #pragma unroll
      for (int r = 0; r < 4; ++r) {
        float pv = __expf(fmaf(acc[i][j][r], RSQRT_D_, -sqv[r])) * RSQRT_M_;
        short bv = f2b(pv);
        outP[(size_t)(row0 + rl + r) * M_ + col0 + cl] = bv;
        tb[r] = bv;
      }
      if (WRITE_T)
        *(short4v*)(smem + (size_t)cl * 136 + rl) = tb;
    }
  }
  if (WRITE_T) {
    __syncthreads();
    int g = row0 >> 8, tb0 = row0 & 255;
    #pragma unroll
    for (int it = 0; it < 8; ++it) {
      int ci = tid + 256 * it;
      int t8 = ci & 15, cc = ci >> 4;
      short8 vv = *(const short8*)(smem + (size_t)cc * 136 + t8 * 8);
      *(short8*)(outT + (size_t)g * (M_*C_) + (size_t)(col0 + cc) * C_ + tb0 + t8 * 8) = vv;
    }
  }
}

// ---- K4: S[g][d][m] = sum_t vT[g][d][t]*kpT[g][m][t], fp32 out ----------
__global__ __launch_bounds__(256) void chunkstate_mfma_kernel(
    const short* __restrict__ vT, const short* __restrict__ kpT,
    float* __restrict__ S)
{
  __shared__ short smem[16384];
  const int g = blockIdx.z, d0 = blockIdx.y * 128, m0 = blockIdx.x * 128;
  floatx4 acc[4][4];
  #pragma unroll
  for (int i = 0; i < 4; ++i)
    #pragma unroll
    for (int j = 0; j < 4; ++j) acc[i][j] = (floatx4){0.f,0.f,0.f,0.f};
  mfma_tile_gemm(vT + (size_t)g * (D_*C_) + (size_t)d0 * C_, C_,
                 kpT + (size_t)g * (M_*C_) + (size_t)m0 * C_, C_, C_,
                 smem, smem + 8192, acc);
  const int tid = threadIdx.x, lane = tid & 63, wave = tid >> 6;
  const int wm = wave >> 1, wn = wave & 1, q = lane >> 4, ln = lane & 15;
  #pragma unroll
  for (int i = 0; i < 4; ++i) {
    int rl = d0 + wm * 64 + i * 16 + q * 4;
    #pragma unroll
    for (int j = 0; j < 4; ++j) {
      int cl = m0 + wn * 64 + j * 16 + ln;
      #pragma unroll
      for (int r = 0; r < 4; ++r)
        S[((size_t)g * D_ + rl + r) * M_ + cl] = acc[i][j][r];
    }
  }
}

// ---- K5: fused z chunk-sum + exclusive chunk prefix ---------------------
__global__ __launch_bounds__(256) void zprefix_kernel(
    const short* __restrict__ kp, float* __restrict__ z)
{
  int j = blockIdx.x * 256 + threadIdx.x;   // 0..2047
  int b = j >> 9, m = j & 511;
  float run = 0.f;
  const short* kb = kp + (size_t)b * NC_ * C_ * M_ + m;
  float* zb = z + (size_t)b * NC_ * M_ + m;
  for (int i = 0; i < NC_; ++i) {
    zb[(size_t)i * M_] = run;
    const short* kc = kb + (size_t)i * C_ * M_;
    float s = 0.f;
    for (int t = 0; t < C_; ++t) s += b2f(kc[(size_t)t * M_]);
    run += s;
  }
}

// ---- K6: exclusive chunk prefix of S (fp32 in) -> Pb (bf16 out) ---------
__global__ __launch_bounds__(256) void prefixS_kernel(
    const float* __restrict__ S, short* __restrict__ Pb)
{
  int j = blockIdx.x * 256 + threadIdx.x;   // 524288
  int b = j >> 17, e = j & 131071;
  float run = 0.f;
  size_t idx = ((size_t)b * NC_) * 131072 + e;
  for (int i = 0; i < NC_; ++i) {
    float t = S[idx];
    Pb[idx] = f2b(run);
    run += t;
    idx += 131072;
  }
}

// ---- K7: Amat[g][t][t'] = masked qp.kp^T, bf16 out ----------------------
__global__ __launch_bounds__(256) void qk_mfma_kernel(
    const short* __restrict__ qp, const short* __restrict__ kp,
    short* __restrict__ Am)
{
  const int g = blockIdx.z;
  const int tt0 = blockIdx.y * 128, tp0 = blockIdx.x * 128;
  short* Ag = Am + (size_t)g * (C_*C_);
  const int tid = threadIdx.x;
  if (tp0 > tt0) {
    short8 z8 = 0;
    #pragma unroll
    for (int it = 0; it < 8; ++it) {
      int ci = tid + 256 * it;
      int row = ci >> 4, c8 = ci & 15;
      *(short8*)(Ag + (size_t)(tt0 + row) * C_ + tp0 + c8 * 8) = z8;
    }
    return;
  }
  __shared__ short smem[16384];
  floatx4 acc[4][4];
  #pragma unroll
  for (int i = 0; i < 4; ++i)
    #pragma unroll
    for (int j = 0; j < 4; ++j) acc[i][j] = (floatx4){0.f,0.f,0.f,0.f};
  const size_t cb = (size_t)g * C_;
  mfma_tile_gemm(qp + (cb + tt0) * M_, M_, kp + (cb + tp0) * M_, M_, M_,
                 smem, smem + 8192, acc);
  const int lane = tid & 63, wave = tid >> 6;
  const int wm = wave >> 1, wn = wave & 1, q = lane >> 4, ln = lane & 15;
  #pragma unroll
  for (int i = 0; i < 4; ++i) {
    int rl = tt0 + wm * 64 + i * 16 + q * 4;
    #pragma unroll
    for (int j = 0; j < 4; ++j) {
      int cl = tp0 + wn * 64 + j * 16 + ln;
      #pragma unroll
      for (int r = 0; r < 4; ++r) {
        short bv = (cl <= rl + r) ? f2b(acc[i][j][r]) : (short)0;
        Ag[(size_t)(rl + r) * C_ + cl] = bv;
      }
    }
  }
}

// ---- K8: den[row] = qp.z_prefix + rowsum(Amat) + eps --------------------
__global__ __launch_bounds__(256) void den_kernel(
    const short* __restrict__ qp, const float* __restrict__ z,
    const short* __restrict__ Am, float* __restrict__ den)
{
  int wid  = blockIdx.x * 4 + (threadIdx.x >> 6);
  int lane = threadIdx.x & 63;
  int g = wid >> 8, tl = wid & 255;
  short8 qv = *(const short8*)(qp + (size_t)wid * M_ + lane * 8);
  const float* zp = z + (size_t)g * M_ + lane * 8;
  float4 z1 = *(const float4*)(zp);
  float4 z2 = *(const float4*)(zp + 4);
  float s = 0.f;
  s = fmaf(b2f(qv[0]), z1.x, s); s = fmaf(b2f(qv[1]), z1.y, s);
  s = fmaf(b2f(qv[2]), z1.z, s); s = fmaf(b2f(qv[3]), z1.w, s);
  s = fmaf(b2f(qv[4]), z2.x, s); s = fmaf(b2f(qv[5]), z2.y, s);
  s = fmaf(b2f(qv[6]), z2.z, s); s = fmaf(b2f(qv[7]), z2.w, s);
  short4v av = *(const short4v*)(Am + (size_t)g * (C_*C_) + (size_t)tl * C_ + lane * 4);
  s += b2f(av.x) + b2f(av.y) + b2f(av.z) + b2f(av.w);
  #pragma unroll
  for (int off = 32; off > 0; off >>= 1) s += __shfl_down(s, off);
  if (lane == 0) den[wid] = s + EPS_;
}

// ---- K9: out = (qp@Pb^T + Amat@vT^T) / den ------------------------------
__global__ __launch_bounds__(256) void out_mfma_kernel(
    const short* __restrict__ qp, const short* __restrict__ Pb,
    const short* __restrict__ Am, const short* __restrict__ vT,
    const float* __restrict__ den, float* __restrict__ out)
{
  __shared__ short smem[16384];
  const int g = blockIdx.z;
  const int tt0 = blockIdx.y * 128, d0 = blockIdx.x * 128;
  floatx4 acc[4][4];
  #pragma unroll
  for (int i = 0; i < 4; ++i)
    #pragma unroll
    for (int j = 0; j < 4; ++j) acc[i][j] = (floatx4){0.f,0.f,0.f,0.f};
  mfma_tile_gemm(qp + ((size_t)g * C_ + tt0) * M_, M_,
                 Pb + (size_t)g * (D_*M_) + (size_t)d0 * M_, M_, M_,
                 smem, smem + 8192, acc);
  mfma_tile_gemm(Am + ((size_t)g * C_ + tt0) * C_, C_,
                 vT + (size_t)g * (D_*C_) + (size_t)d0 * C_, C_, C_,
                 smem, smem + 8192, acc);
  const int tid = threadIdx.x, lane = tid & 63, wave = tid >> 6;
  const int wm = wave >> 1, wn = wave & 1, q = lane >> 4, ln = lane & 15;
  #pragma unroll
  for (int i = 0; i < 4; ++i) {
    int rl = tt0 + wm * 64 + i * 16 + q * 4;
    #pragma unroll
    for (int r = 0; r < 4; ++r) {
      int grow = g * C_ + rl + r;
      float rc = 1.0f / den[grow];
      #pragma unroll
      for (int j = 0; j < 4; ++j) {
        int cl = d0 + wn * 64 + j * 16 + ln;
        out[(size_t)grow * D_ + cl] = acc[i][j][r] * rc;
      }
    }
  }
}

// ---- host-side launch ---------------------------------------------------
extern "C" void kernel_launch(void* const* d_in, const int* in_sizes, int n_in,
                              void* d_out, int out_size, void* d_ws, size_t ws_size,
                              hipStream_t stream) {
  const float* q = (const float*)d_in[0];
  const float* k = (const float*)d_in[1];
  const float* v = (const float*)d_in[2];
  const float* W = (const float*)d_in[3];
  float* out = (float*)d_out;
  char* ws = (char*)d_ws;

  float* S   = (float*)(ws + OFF_S);
  short* Wt  = (short*)(ws + OFF_WT);
  short* qp  = (short*)(ws + OFF_QP);
  short* kp  = (short*)(ws + OFF_KP);
  short* kpT = (short*)(ws + OFF_KPT);
  short* vT  = (short*)(ws + OFF_VT);
  short* Am  = (short*)(ws + OFF_AM);
  short* Pb  = (short*)(ws + OFF_PB);
  float* z   = (float*)(ws + OFF_Z);
  float* den = (float*)(ws + OFF_DEN);

  // W [256k][512n] -> Wt [n][k]
  transpose_cvt_kernel<<<dim3(8, 4, 1), 256, 0, stream>>>(W, Wt, M_, D_, 0, 0);
  // v [g][t][d] -> vT [g][d][t]
  transpose_cvt_kernel<<<dim3(4, 4, NG_), 256, 0, stream>>>(v, vT, D_, C_,
      (long)(C_*D_), (long)(D_*C_));
  phi_mfma_kernel<false><<<dim3(M_/128, (B_*L_)/128), 256, 0, stream>>>(q, Wt, qp, nullptr);
  phi_mfma_kernel<true ><<<dim3(M_/128, (B_*L_)/128), 256, 0, stream>>>(k, Wt, kp, kpT);
  chunkstate_mfma_kernel<<<dim3(M_/128, D_/128, NG_), 256, 0, stream>>>(vT, kpT, S);
  zprefix_kernel<<<8, 256, 0, stream>>>(kp, z);
  prefixS_kernel<<<(B_*D_*M_)/256, 256, 0, stream>>>(S, Pb);
  qk_mfma_kernel<<<dim3(C_/128, C_/128, NG_), 256, 0, stream>>>(qp, kp, Am);
  den_kernel<<<(B_*L_)/4, 256, 0, stream>>>(qp, z, Am, den);
  out_mfma_kernel<<<dim3(D_/128, C_/128, NG_), 256, 0, stream>>>(qp, Pb, Am, vT, den, out);
}

// Round 4
// 219.936 us; speedup vs baseline: 1.3986x; 1.3986x over previous
//
#include <hip/hip_runtime.h>

// ---- problem constants --------------------------------------------------
#define B_ 4
#define L_ 4096
#define D_ 256
#define M_ 512
#define C_ 256
#define NC_ 16
#define NG_ (B_*NC_)
#define EPS_ 1e-6f
#define RSQRT_D_ 0.0625f
#define RSQRT_M_ 0.044194173824159216f

typedef __attribute__((ext_vector_type(8))) short short8;
typedef __attribute__((ext_vector_type(4))) short short4v;
typedef __attribute__((ext_vector_type(4))) float floatx4;

// ---- bf16 helpers (RNE) -------------------------------------------------
__device__ __forceinline__ short f2b(float f) {
  union { float f; unsigned u; } c; c.f = f;
  unsigned r = c.u + 0x7fffu + ((c.u >> 16) & 1u);
  return (short)(r >> 16);
}
__device__ __forceinline__ float b2f(short s) {
  union { unsigned u; float f; } c; c.u = ((unsigned)(unsigned short)s) << 16;
  return c.f;
}

// ---- async 16B global->LDS (wave-uniform LDS base + lane*16) ------------
__device__ __forceinline__ void async_copy16(short* lds, const short* gp) {
  __builtin_amdgcn_global_load_lds(
      (const __attribute__((address_space(1))) unsigned int*)gp,
      (__attribute__((address_space(3))) unsigned int*)(unsigned int)(unsigned long long)lds,
      16, 0, 0);
}

// ---- workspace layout (byte offsets) ------------------------------------
#define OFF_S    0u                 // fp32 [64][256 d][512 m]; Wt aliases head
#define OFF_WT   0u                 // bf16 [512 n][256 k] (dead before chunkstate)
#define OFF_QP   33554432u          // bf16 [16384][512]
#define OFF_KP   50331648u          // bf16 [16384][512]
#define OFF_KPT  67108864u          // bf16 [64][512][256]
#define OFF_VT   83886080u          // bf16 [64][256][256]
#define OFF_AM   92274688u          // bf16 [64][256][256]
#define OFF_ZP   92274688u          // fp32 [64][4][512] z-partials; ALIASES Am,
                                    //   consumed by prefixz BEFORE qk writes Am
#define OFF_PB   100663296u         // bf16 [64][256][512]
#define OFF_Z    117440512u         // fp32 [64][512]
#define OFF_DEN  117571584u         // fp32 [16384]

// ======================================================================
// MFMA GEMM core, GLL staging: C[128x128] += A[128xK] * B[128xK]^T
// A,B row-major bf16 [row][k]. 256 threads = 4 waves (2x2). BK=64.
// LDS slot(m,c) = c*128 + (m^c); GLL lane l sources row m64*64+(l^c) so the
// lane-linear LDS placement lands in the swizzled layout.
// ======================================================================
__device__ __forceinline__ void mfma_tile_gemm(
    const short* __restrict__ Ag, int lda,
    const short* __restrict__ Bg, int ldb,
    int K, short* sA, short* sB, floatx4 acc[4][4])
{
  const int tid  = threadIdx.x;
  const int lane = tid & 63;
  const int wave = tid >> 6;
  const int wm = wave >> 1, wn = wave & 1;
  const int q = lane >> 4, ml = lane & 15;

  for (int k0 = 0; k0 < K; k0 += 64) {
    #pragma unroll
    for (int n = 0; n < 4; ++n) {
      int idx = wave * 4 + n;            // 0..15
      int c = idx >> 1, m64 = idx & 1;
      int m = m64 * 64 + (lane ^ c);
      async_copy16(sA + (c * 128 + m64 * 64) * 8,
                   Ag + (size_t)m * lda + k0 + c * 8);
      async_copy16(sB + (c * 128 + m64 * 64) * 8,
                   Bg + (size_t)m * ldb + k0 + c * 8);
    }
    __syncthreads();
    #pragma unroll
    for (int ks = 0; ks < 2; ++ks) {
      short8 a[4], b[4];
      int c = ks * 4 + q;
      #pragma unroll
      for (int i = 0; i < 4; ++i) {
        int ra = (wm * 64 + i * 16 + ml) ^ c;
        a[i] = *(const short8*)(sA + (c * 128 + ra) * 8);
        int rb = (wn * 64 + i * 16 + ml) ^ c;
        b[i] = *(const short8*)(sB + (c * 128 + rb) * 8);
      }
      #pragma unroll
      for (int i = 0; i < 4; ++i)
        #pragma unroll
        for (int j = 0; j < 4; ++j)
          acc[i][j] = __builtin_amdgcn_mfma_f32_16x16x32_bf16(a[i], b[j], acc[i][j], 0, 0, 0);
    }
    __syncthreads();
  }
}

// ---- K1: generic fp32 [r][c] -> bf16 [c][r] tile transpose --------------
__global__ __launch_bounds__(256) void transpose_cvt_kernel(
    const float* __restrict__ in, short* __restrict__ out,
    int ld_in, int ld_out, long sg_in, long sg_out)
{
  __shared__ short sm[64 * 65];
  const int g = blockIdx.z;
  const int r0 = blockIdx.y * 64, c0 = blockIdx.x * 64;
  const float* src = in + (size_t)g * sg_in + (size_t)r0 * ld_in + c0;
  short* dst = out + (size_t)g * sg_out + (size_t)c0 * ld_out + r0;
  const int tid = threadIdx.x;
  #pragma unroll
  for (int it = 0; it < 4; ++it) {
    int ci = tid + 256 * it;
    int row = ci >> 4, c4 = ci & 15;
    float4 x = *(const float4*)(src + (size_t)row * ld_in + c4 * 4);
    sm[(c4 * 4 + 0) * 65 + row] = f2b(x.x);
    sm[(c4 * 4 + 1) * 65 + row] = f2b(x.y);
    sm[(c4 * 4 + 2) * 65 + row] = f2b(x.z);
    sm[(c4 * 4 + 3) * 65 + row] = f2b(x.w);
  }
  __syncthreads();
  #pragma unroll
  for (int it = 0; it < 2; ++it) {
    int ci = tid + 256 * it;
    int dr = ci >> 3, t8 = ci & 7;
    short8 o;
    #pragma unroll
    for (int u = 0; u < 8; ++u) o[u] = sm[dr * 65 + t8 * 8 + u];
    *(short8*)(dst + (size_t)dr * ld_out + t8 * 8) = o;
  }
}

// ---- K2/K3: phi = exp(X@W/sqrt(d) - 0.5||x||^2)/sqrt(M), fused cvt+ssq --
template<bool WRITE_T>
__global__ __launch_bounds__(256) void phi_mfma_kernel(
    const float* __restrict__ X, const short* __restrict__ Wt,
    short* __restrict__ outP, short* __restrict__ outT)
{
  __shared__ short smem[17664];   // sA 8192 | sB 8192 | tbuf overlaps | sqs @17408
  short* sA = smem;
  short* sB = smem + 8192;
  float* sqs = (float*)(smem + 17408);
  const int row0 = blockIdx.y * 128, col0 = blockIdx.x * 128;
  const int tid = threadIdx.x, lane = tid & 63, wave = tid >> 6;
  const int wm = wave >> 1, wn = wave & 1, q = lane >> 4, ml = lane & 15;
  floatx4 acc[4][4];
  #pragma unroll
  for (int i = 0; i < 4; ++i)
    #pragma unroll
    for (int j = 0; j < 4; ++j) acc[i][j] = (floatx4){0.f,0.f,0.f,0.f};

  float ssq[4] = {0.f, 0.f, 0.f, 0.f};
  for (int k0 = 0; k0 < D_; k0 += 64) {
    #pragma unroll
    for (int it = 0; it < 4; ++it) {
      int ci = tid + 256 * it;
      int m = ci >> 3, c = ci & 7;
      const float* src = X + (size_t)(row0 + m) * D_ + k0 + c * 8;
      float4 x0 = *(const float4*)src;
      float4 x1 = *(const float4*)(src + 4);
      short8 vv;
      vv[0] = f2b(x0.x); vv[1] = f2b(x0.y); vv[2] = f2b(x0.z); vv[3] = f2b(x0.w);
      vv[4] = f2b(x1.x); vv[5] = f2b(x1.y); vv[6] = f2b(x1.z); vv[7] = f2b(x1.w);
      ssq[it] += x0.x*x0.x + x0.y*x0.y + x0.z*x0.z + x0.w*x0.w
               + x1.x*x1.x + x1.y*x1.y + x1.z*x1.z + x1.w*x1.w;
      *(short8*)(sA + (c * 128 + (m ^ c)) * 8) = vv;
    }
    #pragma unroll
    for (int n = 0; n < 4; ++n) {
      int idx = wave * 4 + n;
      int c = idx >> 1, m64 = idx & 1;
      async_copy16(sB + (c * 128 + m64 * 64) * 8,
                   Wt + (size_t)(col0 + m64 * 64 + (lane ^ c)) * D_ + k0 + c * 8);
    }
    __syncthreads();
    #pragma unroll
    for (int ks = 0; ks < 2; ++ks) {
      short8 a[4], b[4];
      int c = ks * 4 + q;
      #pragma unroll
      for (int i = 0; i < 4; ++i) {
        int ra = (wm * 64 + i * 16 + ml) ^ c;
        a[i] = *(const short8*)(sA + (c * 128 + ra) * 8);
        int rb = (wn * 64 + i * 16 + ml) ^ c;
        b[i] = *(const short8*)(sB + (c * 128 + rb) * 8);
      }
      #pragma unroll
      for (int i = 0; i < 4; ++i)
        #pragma unroll
        for (int j = 0; j < 4; ++j)
          acc[i][j] = __builtin_amdgcn_mfma_f32_16x16x32_bf16(a[i], b[j], acc[i][j], 0, 0, 0);
    }
    __syncthreads();
  }
  // reduce ssq across the 8 threads sharing tid>>3 (consecutive lanes)
  #pragma unroll
  for (int o = 1; o < 8; o <<= 1)
    #pragma unroll
    for (int it = 0; it < 4; ++it) ssq[it] += __shfl_xor(ssq[it], o);
  if ((tid & 7) == 0) {
    #pragma unroll
    for (int it = 0; it < 4; ++it) sqs[(tid >> 3) + 32 * it] = 0.5f * ssq[it];
  }
  __syncthreads();
  // epilogue
  #pragma unroll
  for (int i = 0; i < 4; ++i) {
    int rl = wm * 64 + i * 16 + q * 4;
    float sqv[4];
    #pragma unroll
    for (int r = 0; r < 4; ++r) sqv[r] = sqs[rl + r];
    #pragma unroll
    for (int j = 0; j < 4; ++j) {
      int cl = wn * 64 + j * 16 + ml;
      short4v tb;
      #pragma unroll
      for (int r = 0; r < 4; ++r) {
        float pv = __expf(fmaf(acc[i][j][r], RSQRT_D_, -sqv[r])) * RSQRT_M_;
        short bv = f2b(pv);
        outP[(size_t)(row0 + rl + r) * M_ + col0 + cl] = bv;
        tb[r] = bv;
      }
      if (WRITE_T)
        *(short4v*)(smem + (size_t)cl * 136 + rl) = tb;
    }
  }
  if (WRITE_T) {
    __syncthreads();
    int g = row0 >> 8, tb0 = row0 & 255;
    #pragma unroll
    for (int it = 0; it < 8; ++it) {
      int ci = tid + 256 * it;
      int t8 = ci & 15, cc = ci >> 4;
      short8 vv = *(const short8*)(smem + (size_t)cc * 136 + t8 * 8);
      *(short8*)(outT + (size_t)g * (M_*C_) + (size_t)(col0 + cc) * C_ + tb0 + t8 * 8) = vv;
    }
  }
}

// ---- K4: S[g][d][m] = sum_t vT[g][d][t]*kpT[g][m][t], fp32 out ----------
__global__ __launch_bounds__(256) void chunkstate_mfma_kernel(
    const short* __restrict__ vT, const short* __restrict__ kpT,
    float* __restrict__ S)
{
  __shared__ short smem[16384];
  const int g = blockIdx.z, d0 = blockIdx.y * 128, m0 = blockIdx.x * 128;
  floatx4 acc[4][4];
  #pragma unroll
  for (int i = 0; i < 4; ++i)
    #pragma unroll
    for (int j = 0; j < 4; ++j) acc[i][j] = (floatx4){0.f,0.f,0.f,0.f};
  mfma_tile_gemm(vT + (size_t)g * (D_*C_) + (size_t)d0 * C_, C_,
                 kpT + (size_t)g * (M_*C_) + (size_t)m0 * C_, C_, C_,
                 smem, smem + 8192, acc);
  const int tid = threadIdx.x, lane = tid & 63, wave = tid >> 6;
  const int wm = wave >> 1, wn = wave & 1, q = lane >> 4, ln = lane & 15;
  #pragma unroll
  for (int i = 0; i < 4; ++i) {
    int rl = d0 + wm * 64 + i * 16 + q * 4;
    #pragma unroll
    for (int j = 0; j < 4; ++j) {
      int cl = m0 + wn * 64 + j * 16 + ln;
      #pragma unroll
      for (int r = 0; r < 4; ++r)
        S[((size_t)g * D_ + rl + r) * M_ + cl] = acc[i][j][r];
    }
  }
}

// ---- K5a: z partials: ZP[g][p][m] = sum of 64 rows of kp chunk ----------
__global__ __launch_bounds__(256) void zsum_part_kernel(
    const short* __restrict__ kp, float* __restrict__ ZP)
{
  const int mb = blockIdx.x, p = blockIdx.y, g = blockIdx.z;
  const int m = mb * 256 + threadIdx.x;
  const short* base = kp + ((size_t)g * C_ + p * 64) * M_ + m;
  float s = 0.f;
  #pragma unroll 8
  for (int t = 0; t < 64; ++t) s += b2f(base[(size_t)t * M_]);
  ZP[((size_t)g * 4 + p) * M_ + m] = s;
}

// ---- K5b: z[b][i][m] = exclusive chunk prefix of folded partials --------
__global__ __launch_bounds__(256) void prefixz_kernel(
    const float* __restrict__ ZP, float* __restrict__ z)
{
  int j = blockIdx.x * 256 + threadIdx.x;   // 0..2047
  int b = j >> 9, m = j & 511;
  float run = 0.f;
  for (int i = 0; i < NC_; ++i) {
    int g = b * NC_ + i;
    z[(size_t)g * M_ + m] = run;
    const float* zp = ZP + (size_t)g * 4 * M_ + m;
    run += zp[0] + zp[M_] + zp[2*M_] + zp[3*M_];
  }
}

// ---- K6: exclusive chunk prefix of S (fp32 in) -> Pb (bf16 out) ---------
__global__ __launch_bounds__(256) void prefixS_kernel(
    const float* __restrict__ S, short* __restrict__ Pb)
{
  int j = blockIdx.x * 256 + threadIdx.x;   // 524288
  int b = j >> 17, e = j & 131071;
  float run = 0.f;
  size_t idx = ((size_t)b * NC_) * 131072 + e;
  for (int i = 0; i < NC_; ++i) {
    float t = S[idx];
    Pb[idx] = f2b(run);
    run += t;
    idx += 131072;
  }
}

// ---- K7: Amat[g][t][t'] = masked qp.kp^T, bf16 out ----------------------
__global__ __launch_bounds__(256) void qk_mfma_kernel(
    const short* __restrict__ qp, const short* __restrict__ kp,
    short* __restrict__ Am)
{
  const int g = blockIdx.z;
  const int tt0 = blockIdx.y * 128, tp0 = blockIdx.x * 128;
  short* Ag = Am + (size_t)g * (C_*C_);
  const int tid = threadIdx.x;
  if (tp0 > tt0) {
    short8 z8 = 0;
    #pragma unroll
    for (int it = 0; it < 8; ++it) {
      int ci = tid + 256 * it;
      int row = ci >> 4, c8 = ci & 15;
      *(short8*)(Ag + (size_t)(tt0 + row) * C_ + tp0 + c8 * 8) = z8;
    }
    return;
  }
  __shared__ short smem[16384];
  floatx4 acc[4][4];
  #pragma unroll
  for (int i = 0; i < 4; ++i)
    #pragma unroll
    for (int j = 0; j < 4; ++j) acc[i][j] = (floatx4){0.f,0.f,0.f,0.f};
  const size_t cb = (size_t)g * C_;
  mfma_tile_gemm(qp + (cb + tt0) * M_, M_, kp + (cb + tp0) * M_, M_, M_,
                 smem, smem + 8192, acc);
  const int lane = tid & 63, wave = tid >> 6;
  const int wm = wave >> 1, wn = wave & 1, q = lane >> 4, ln = lane & 15;
  #pragma unroll
  for (int i = 0; i < 4; ++i) {
    int rl = tt0 + wm * 64 + i * 16 + q * 4;
    #pragma unroll
    for (int j = 0; j < 4; ++j) {
      int cl = tp0 + wn * 64 + j * 16 + ln;
      #pragma unroll
      for (int r = 0; r < 4; ++r) {
        short bv = (cl <= rl + r) ? f2b(acc[i][j][r]) : (short)0;
        Ag[(size_t)(rl + r) * C_ + cl] = bv;
      }
    }
  }
}

// ---- K8: den[row] = qp.z_prefix + rowsum(Amat) + eps --------------------
__global__ __launch_bounds__(256) void den_kernel(
    const short* __restrict__ qp, const float* __restrict__ z,
    const short* __restrict__ Am, float* __restrict__ den)
{
  int wid  = blockIdx.x * 4 + (threadIdx.x >> 6);
  int lane = threadIdx.x & 63;
  int g = wid >> 8, tl = wid & 255;
  short8 qv = *(const short8*)(qp + (size_t)wid * M_ + lane * 8);
  const float* zp = z + (size_t)g * M_ + lane * 8;
  float4 z1 = *(const float4*)(zp);
  float4 z2 = *(const float4*)(zp + 4);
  float s = 0.f;
  s = fmaf(b2f(qv[0]), z1.x, s); s = fmaf(b2f(qv[1]), z1.y, s);
  s = fmaf(b2f(qv[2]), z1.z, s); s = fmaf(b2f(qv[3]), z1.w, s);
  s = fmaf(b2f(qv[4]), z2.x, s); s = fmaf(b2f(qv[5]), z2.y, s);
  s = fmaf(b2f(qv[6]), z2.z, s); s = fmaf(b2f(qv[7]), z2.w, s);
  short4v av = *(const short4v*)(Am + (size_t)g * (C_*C_) + (size_t)tl * C_ + lane * 4);
  s += b2f(av.x) + b2f(av.y) + b2f(av.z) + b2f(av.w);
  #pragma unroll
  for (int off = 32; off > 0; off >>= 1) s += __shfl_down(s, off);
  if (lane == 0) den[wid] = s + EPS_;
}

// ---- K9: out = (qp@Pb^T + Amat@vT^T) / den ------------------------------
__global__ __launch_bounds__(256) void out_mfma_kernel(
    const short* __restrict__ qp, const short* __restrict__ Pb,
    const short* __restrict__ Am, const short* __restrict__ vT,
    const float* __restrict__ den, float* __restrict__ out)
{
  __shared__ short smem[16384];
  const int g = blockIdx.z;
  const int tt0 = blockIdx.y * 128, d0 = blockIdx.x * 128;
  floatx4 acc[4][4];
  #pragma unroll
  for (int i = 0; i < 4; ++i)
    #pragma unroll
    for (int j = 0; j < 4; ++j) acc[i][j] = (floatx4){0.f,0.f,0.f,0.f};
  mfma_tile_gemm(qp + ((size_t)g * C_ + tt0) * M_, M_,
                 Pb + (size_t)g * (D_*M_) + (size_t)d0 * M_, M_, M_,
                 smem, smem + 8192, acc);
  mfma_tile_gemm(Am + ((size_t)g * C_ + tt0) * C_, C_,
                 vT + (size_t)g * (D_*C_) + (size_t)d0 * C_, C_, C_,
                 smem, smem + 8192, acc);
  const int tid = threadIdx.x, lane = tid & 63, wave = tid >> 6;
  const int wm = wave >> 1, wn = wave & 1, q = lane >> 4, ln = lane & 15;
  #pragma unroll
  for (int i = 0; i < 4; ++i) {
    int rl = tt0 + wm * 64 + i * 16 + q * 4;
    #pragma unroll
    for (int r = 0; r < 4; ++r) {
      int grow = g * C_ + rl + r;
      float rc = 1.0f / den[grow];
      #pragma unroll
      for (int j = 0; j < 4; ++j) {
        int cl = d0 + wn * 64 + j * 16 + ln;
        out[(size_t)grow * D_ + cl] = acc[i][j][r] * rc;
      }
    }
  }
}

// ---- host-side launch ---------------------------------------------------
extern "C" void kernel_launch(void* const* d_in, const int* in_sizes, int n_in,
                              void* d_out, int out_size, void* d_ws, size_t ws_size,
                              hipStream_t stream) {
  const float* q = (const float*)d_in[0];
  const float* k = (const float*)d_in[1];
  const float* v = (const float*)d_in[2];
  const float* W = (const float*)d_in[3];
  float* out = (float*)d_out;
  char* ws = (char*)d_ws;

  float* S   = (float*)(ws + OFF_S);
  short* Wt  = (short*)(ws + OFF_WT);
  short* qp  = (short*)(ws + OFF_QP);
  short* kp  = (short*)(ws + OFF_KP);
  short* kpT = (short*)(ws + OFF_KPT);
  short* vT  = (short*)(ws + OFF_VT);
  short* Am  = (short*)(ws + OFF_AM);
  float* ZP  = (float*)(ws + OFF_ZP);
  short* Pb  = (short*)(ws + OFF_PB);
  float* z   = (float*)(ws + OFF_Z);
  float* den = (float*)(ws + OFF_DEN);

  // W [256k][512n] -> Wt [n][k]
  transpose_cvt_kernel<<<dim3(8, 4, 1), 256, 0, stream>>>(W, Wt, M_, D_, 0, 0);
  // v [g][t][d] -> vT [g][d][t]
  transpose_cvt_kernel<<<dim3(4, 4, NG_), 256, 0, stream>>>(v, vT, D_, C_,
      (long)(C_*D_), (long)(D_*C_));
  phi_mfma_kernel<false><<<dim3(M_/128, (B_*L_)/128), 256, 0, stream>>>(q, Wt, qp, nullptr);
  phi_mfma_kernel<true ><<<dim3(M_/128, (B_*L_)/128), 256, 0, stream>>>(k, Wt, kp, kpT);
  chunkstate_mfma_kernel<<<dim3(M_/128, D_/128, NG_), 256, 0, stream>>>(vT, kpT, S);
  // z partials (ZP aliases Am; prefixz consumes before qk writes Am)
  zsum_part_kernel<<<dim3(2, 4, NG_), 256, 0, stream>>>(kp, ZP);
  prefixz_kernel<<<8, 256, 0, stream>>>(ZP, z);
  prefixS_kernel<<<(B_*D_*M_)/256, 256, 0, stream>>>(S, Pb);
  qk_mfma_kernel<<<dim3(C_/128, C_/128, NG_), 256, 0, stream>>>(qp, kp, Am);
  den_kernel<<<(B_*L_)/4, 256, 0, stream>>>(qp, z, Am, den);
  out_mfma_kernel<<<dim3(D_/128, C_/128, NG_), 256, 0, stream>>>(qp, Pb, Am, vT, den, out);
}

// Round 5
// 211.893 us; speedup vs baseline: 1.4517x; 1.0380x over previous
//
#include <hip/hip_runtime.h>

// ---- problem constants --------------------------------------------------
#define B_ 4
#define L_ 4096
#define D_ 256
#define M_ 512
#define C_ 256
#define NC_ 16
#define NG_ (B_*NC_)
#define EPS_ 1e-6f
#define RSQRT_D_ 0.0625f
#define RSQRT_M_ 0.044194173824159216f

typedef __attribute__((ext_vector_type(8))) short short8;
typedef __attribute__((ext_vector_type(4))) short short4v;
typedef __attribute__((ext_vector_type(4))) float floatx4;

// ---- bf16 helpers (RNE) -------------------------------------------------
__device__ __forceinline__ short f2b(float f) {
  union { float f; unsigned u; } c; c.f = f;
  unsigned r = c.u + 0x7fffu + ((c.u >> 16) & 1u);
  return (short)(r >> 16);
}
__device__ __forceinline__ float b2f(short s) {
  union { unsigned u; float f; } c; c.u = ((unsigned)(unsigned short)s) << 16;
  return c.f;
}

// ---- workspace layout (byte offsets) ------------------------------------
#define OFF_S    0u                 // fp32 [64][256 d][512 m]; Wt aliases head
#define OFF_WT   0u                 // bf16 [512 n][256 k] (dead before chunkstate)
#define OFF_QP   33554432u          // bf16 [16384][512]
#define OFF_KP   50331648u          // bf16 [16384][512]
#define OFF_KPT  67108864u          // bf16 [64][512][256]
#define OFF_VT   83886080u          // bf16 [64][256][256]
#define OFF_AM   92274688u          // bf16 [64][256][256]
#define OFF_ZP   92274688u          // fp32 [64][4][512] z-partials; ALIASES Am,
                                    //   consumed by prefixz BEFORE qk writes Am
#define OFF_PB   100663296u         // bf16 [64][256][512]
#define OFF_Z    117440512u         // fp32 [64][512]
#define OFF_DEN  117571584u         // fp32 [16384]

// ======================================================================
// MFMA GEMM core (round-2 proven): C[128x128] += A[128xK] * B[128xK]^T
// A,B row-major bf16 [row][k]. 256 threads = 4 waves (2x2). BK=64.
// Manual staging: coalesced 16B global loads (8 lanes = 128B contiguous)
// -> XOR-swizzled ds_write_b128 -> conflict-free ds_read_b128 fragments.
// GLL rejected: coalesced GLL forces row-major LDS (16-way read conflicts);
// swizzled-source GLL breaks global coalescing (round 3/4 regression).
// ======================================================================
__device__ __forceinline__ void mfma_tile_gemm(
    const short* __restrict__ Ag, int lda,
    const short* __restrict__ Bg, int ldb,
    int K, short* sA, short* sB, floatx4 acc[4][4])
{
  const int tid  = threadIdx.x;
  const int lane = tid & 63;
  const int wave = tid >> 6;
  const int wm = wave >> 1, wn = wave & 1;
  const int q = lane >> 4, ml = lane & 15;

  for (int k0 = 0; k0 < K; k0 += 64) {
    #pragma unroll
    for (int it = 0; it < 4; ++it) {
      int ci = tid + 256 * it;          // 0..1023
      int m  = ci >> 3;                 // 0..127
      int k8 = ci & 7;                  // 16B chunk within 64-k
      short8 va = *(const short8*)(Ag + (size_t)m * lda + k0 + k8 * 8);
      short8 vb = *(const short8*)(Bg + (size_t)m * ldb + k0 + k8 * 8);
      int dst = (k8 >> 2) * 512 + (m >> 4) * 64 + (k8 & 3) * 16 + ((m & 15) ^ k8);
      *(short8*)(sA + dst * 8) = va;
      *(short8*)(sB + dst * 8) = vb;
    }
    __syncthreads();
    #pragma unroll
    for (int ks = 0; ks < 2; ++ks) {
      short8 a[4], b[4];
      int k8 = ks * 4 + q;
      #pragma unroll
      for (int i = 0; i < 4; ++i) {
        int ca = ks * 512 + (wm * 4 + i) * 64 + q * 16 + (ml ^ k8);
        a[i] = *(const short8*)(sA + ca * 8);
        int cb = ks * 512 + (wn * 4 + i) * 64 + q * 16 + (ml ^ k8);
        b[i] = *(const short8*)(sB + cb * 8);
      }
      #pragma unroll
      for (int i = 0; i < 4; ++i)
        #pragma unroll
        for (int j = 0; j < 4; ++j)
          acc[i][j] = __builtin_amdgcn_mfma_f32_16x16x32_bf16(a[i], b[j], acc[i][j], 0, 0, 0);
    }
    __syncthreads();
  }
}

// ---- K1: combined transpose+cvt: v (z<NG_) and W (z==NG_) ---------------
__global__ __launch_bounds__(256) void transpose_cvt_kernel(
    const float* __restrict__ v, const float* __restrict__ W,
    short* __restrict__ vT, short* __restrict__ Wt)
{
  const int z = blockIdx.z;
  const float* src; short* dst; int ld_in, ld_out;
  if (z < NG_) {
    if (blockIdx.x >= 4) return;     // v uses 4x4 tiles; W grid x is 8-wide
    src = v + (size_t)z * (C_*D_) + (size_t)blockIdx.y * 64 * D_ + blockIdx.x * 64;
    dst = vT + (size_t)z * (D_*C_) + (size_t)blockIdx.x * 64 * C_ + blockIdx.y * 64;
    ld_in = D_; ld_out = C_;
  } else {
    src = W + (size_t)blockIdx.y * 64 * M_ + blockIdx.x * 64;
    dst = Wt + (size_t)blockIdx.x * 64 * D_ + blockIdx.y * 64;
    ld_in = M_; ld_out = D_;
  }
  __shared__ short sm[64 * 65];
  const int tid = threadIdx.x;
  #pragma unroll
  for (int it = 0; it < 4; ++it) {
    int ci = tid + 256 * it;
    int row = ci >> 4, c4 = ci & 15;
    float4 x = *(const float4*)(src + (size_t)row * ld_in + c4 * 4);
    sm[(c4 * 4 + 0) * 65 + row] = f2b(x.x);
    sm[(c4 * 4 + 1) * 65 + row] = f2b(x.y);
    sm[(c4 * 4 + 2) * 65 + row] = f2b(x.z);
    sm[(c4 * 4 + 3) * 65 + row] = f2b(x.w);
  }
  __syncthreads();
  #pragma unroll
  for (int it = 0; it < 2; ++it) {
    int ci = tid + 256 * it;
    int dr = ci >> 3, t8 = ci & 7;
    short8 o;
    #pragma unroll
    for (int u = 0; u < 8; ++u) o[u] = sm[dr * 65 + t8 * 8 + u];
    *(short8*)(dst + (size_t)dr * ld_out + t8 * 8) = o;
  }
}

// ---- K2: merged q/k phi = exp(X@W/sqrt(d) - 0.5||x||^2)/sqrt(M) ---------
// blockIdx.z: 0 -> q (no transpose out), 1 -> k (also writes kpT).
// A operand: fp32 global (coalesced) -> cvt -> swizzled ds_write; in-kernel
// row ssq (per-thread partials -> 8-lane shuffle -> LDS).
__global__ __launch_bounds__(256) void phi_mfma_kernel(
    const float* __restrict__ qin, const float* __restrict__ kin,
    const short* __restrict__ Wt,
    short* __restrict__ qp, short* __restrict__ kp, short* __restrict__ kpT)
{
  const bool is_k = (blockIdx.z == 1);
  const float* X = is_k ? kin : qin;
  short* outP = is_k ? kp : qp;
  __shared__ short smem[17664];   // sA 8192 | sB 8192 | tbuf overlaps | sqs @17408
  short* sA = smem;
  short* sB = smem + 8192;
  float* sqs = (float*)(smem + 17408);
  const int row0 = blockIdx.y * 128, col0 = blockIdx.x * 128;
  const int tid = threadIdx.x, lane = tid & 63, wave = tid >> 6;
  const int wm = wave >> 1, wn = wave & 1, q = lane >> 4, ml = lane & 15;
  floatx4 acc[4][4];
  #pragma unroll
  for (int i = 0; i < 4; ++i)
    #pragma unroll
    for (int j = 0; j < 4; ++j) acc[i][j] = (floatx4){0.f,0.f,0.f,0.f};

  float ssq[4] = {0.f, 0.f, 0.f, 0.f};
  for (int k0 = 0; k0 < D_; k0 += 64) {
    #pragma unroll
    for (int it = 0; it < 4; ++it) {
      int ci = tid + 256 * it;
      int m = ci >> 3, c = ci & 7;
      const float* src = X + (size_t)(row0 + m) * D_ + k0 + c * 8;
      float4 x0 = *(const float4*)src;
      float4 x1 = *(const float4*)(src + 4);
      short8 vv;
      vv[0] = f2b(x0.x); vv[1] = f2b(x0.y); vv[2] = f2b(x0.z); vv[3] = f2b(x0.w);
      vv[4] = f2b(x1.x); vv[5] = f2b(x1.y); vv[6] = f2b(x1.z); vv[7] = f2b(x1.w);
      ssq[it] += x0.x*x0.x + x0.y*x0.y + x0.z*x0.z + x0.w*x0.w
               + x1.x*x1.x + x1.y*x1.y + x1.z*x1.z + x1.w*x1.w;
      *(short8*)(sA + (c * 128 + (m ^ c)) * 8) = vv;
      short8 wb = *(const short8*)(Wt + (size_t)(col0 + m) * D_ + k0 + c * 8);
      *(short8*)(sB + (c * 128 + (m ^ c)) * 8) = wb;
    }
    __syncthreads();
    #pragma unroll
    for (int ks = 0; ks < 2; ++ks) {
      short8 a[4], b[4];
      int c = ks * 4 + q;
      #pragma unroll
      for (int i = 0; i < 4; ++i) {
        int ra = (wm * 64 + i * 16 + ml) ^ c;
        a[i] = *(const short8*)(sA + (c * 128 + ra) * 8);
        int rb = (wn * 64 + i * 16 + ml) ^ c;
        b[i] = *(const short8*)(sB + (c * 128 + rb) * 8);
      }
      #pragma unroll
      for (int i = 0; i < 4; ++i)
        #pragma unroll
        for (int j = 0; j < 4; ++j)
          acc[i][j] = __builtin_amdgcn_mfma_f32_16x16x32_bf16(a[i], b[j], acc[i][j], 0, 0, 0);
    }
    __syncthreads();
  }
  // reduce ssq across the 8 threads sharing tid>>3 (consecutive lanes)
  #pragma unroll
  for (int o = 1; o < 8; o <<= 1)
    #pragma unroll
    for (int it = 0; it < 4; ++it) ssq[it] += __shfl_xor(ssq[it], o);
  if ((tid & 7) == 0) {
    #pragma unroll
    for (int it = 0; it < 4; ++it) sqs[(tid >> 3) + 32 * it] = 0.5f * ssq[it];
  }
  __syncthreads();
  // epilogue
  #pragma unroll
  for (int i = 0; i < 4; ++i) {
    int rl = wm * 64 + i * 16 + q * 4;
    float sqv[4];
    #pragma unroll
    for (int r = 0; r < 4; ++r) sqv[r] = sqs[rl + r];
    #pragma unroll
    for (int j = 0; j < 4; ++j) {
      int cl = wn * 64 + j * 16 + ml;
      short4v tb;
      #pragma unroll
      for (int r = 0; r < 4; ++r) {
        float pv = __expf(fmaf(acc[i][j][r], RSQRT_D_, -sqv[r])) * RSQRT_M_;
        short bv = f2b(pv);
        outP[(size_t)(row0 + rl + r) * M_ + col0 + cl] = bv;
        tb[r] = bv;
      }
      if (is_k)   // col-major LDS [col][row+pad8] for transposed write
        *(short4v*)(smem + (size_t)cl * 136 + rl) = tb;
    }
  }
  if (is_k) {
    __syncthreads();
    int g = row0 >> 8, tb0 = row0 & 255;
    #pragma unroll
    for (int it = 0; it < 8; ++it) {
      int ci = tid + 256 * it;
      int t8 = ci & 15, cc = ci >> 4;
      short8 vv = *(const short8*)(smem + (size_t)cc * 136 + t8 * 8);
      *(short8*)(kpT + (size_t)g * (M_*C_) + (size_t)(col0 + cc) * C_ + tb0 + t8 * 8) = vv;
    }
  }
}

// ---- K3: S[g][d][m] = sum_t vT[g][d][t]*kpT[g][m][t], fp32 out ----------
__global__ __launch_bounds__(256) void chunkstate_mfma_kernel(
    const short* __restrict__ vT, const short* __restrict__ kpT,
    float* __restrict__ S)
{
  __shared__ short smem[16384];
  const int g = blockIdx.z, d0 = blockIdx.y * 128, m0 = blockIdx.x * 128;
  floatx4 acc[4][4];
  #pragma unroll
  for (int i = 0; i < 4; ++i)
    #pragma unroll
    for (int j = 0; j < 4; ++j) acc[i][j] = (floatx4){0.f,0.f,0.f,0.f};
  mfma_tile_gemm(vT + (size_t)g * (D_*C_) + (size_t)d0 * C_, C_,
                 kpT + (size_t)g * (M_*C_) + (size_t)m0 * C_, C_, C_,
                 smem, smem + 8192, acc);
  const int tid = threadIdx.x, lane = tid & 63, wave = tid >> 6;
  const int wm = wave >> 1, wn = wave & 1, q = lane >> 4, ln = lane & 15;
  #pragma unroll
  for (int i = 0; i < 4; ++i) {
    int rl = d0 + wm * 64 + i * 16 + q * 4;
    #pragma unroll
    for (int j = 0; j < 4; ++j) {
      int cl = m0 + wn * 64 + j * 16 + ln;
      #pragma unroll
      for (int r = 0; r < 4; ++r)
        S[((size_t)g * D_ + rl + r) * M_ + cl] = acc[i][j][r];
    }
  }
}

// ---- K4a: z partials: ZP[g][p][m] = sum of 64 rows of kp chunk ----------
__global__ __launch_bounds__(256) void zsum_part_kernel(
    const short* __restrict__ kp, float* __restrict__ ZP)
{
  const int mb = blockIdx.x, p = blockIdx.y, g = blockIdx.z;
  const int m = mb * 256 + threadIdx.x;
  const short* base = kp + ((size_t)g * C_ + p * 64) * M_ + m;
  float s = 0.f;
  #pragma unroll 8
  for (int t = 0; t < 64; ++t) s += b2f(base[(size_t)t * M_]);
  ZP[((size_t)g * 4 + p) * M_ + m] = s;
}

// ---- K4b: z[b][i][m] = exclusive chunk prefix of folded partials --------
__global__ __launch_bounds__(256) void prefixz_kernel(
    const float* __restrict__ ZP, float* __restrict__ z)
{
  int j = blockIdx.x * 256 + threadIdx.x;   // 0..2047
  int b = j >> 9, m = j & 511;
  float run = 0.f;
  for (int i = 0; i < NC_; ++i) {
    int g = b * NC_ + i;
    z[(size_t)g * M_ + m] = run;
    const float* zp = ZP + (size_t)g * 4 * M_ + m;
    run += zp[0] + zp[M_] + zp[2*M_] + zp[3*M_];
  }
}

// ---- K5: exclusive chunk prefix of S (fp32 in) -> Pb (bf16 out) ---------
__global__ __launch_bounds__(256) void prefixS_kernel(
    const float* __restrict__ S, short* __restrict__ Pb)
{
  int j = blockIdx.x * 256 + threadIdx.x;   // 524288
  int b = j >> 17, e = j & 131071;
  float run = 0.f;
  size_t idx = ((size_t)b * NC_) * 131072 + e;
  for (int i = 0; i < NC_; ++i) {
    float t = S[idx];
    Pb[idx] = f2b(run);
    run += t;
    idx += 131072;
  }
}

// ---- K6: Amat[g][t][t'] = masked qp.kp^T, bf16 out ----------------------
__global__ __launch_bounds__(256) void qk_mfma_kernel(
    const short* __restrict__ qp, const short* __restrict__ kp,
    short* __restrict__ Am)
{
  const int g = blockIdx.z;
  const int tt0 = blockIdx.y * 128, tp0 = blockIdx.x * 128;
  short* Ag = Am + (size_t)g * (C_*C_);
  const int tid = threadIdx.x;
  if (tp0 > tt0) {
    short8 z8 = 0;
    #pragma unroll
    for (int it = 0; it < 8; ++it) {
      int ci = tid + 256 * it;
      int row = ci >> 4, c8 = ci & 15;
      *(short8*)(Ag + (size_t)(tt0 + row) * C_ + tp0 + c8 * 8) = z8;
    }
    return;
  }
  __shared__ short smem[16384];
  floatx4 acc[4][4];
  #pragma unroll
  for (int i = 0; i < 4; ++i)
    #pragma unroll
    for (int j = 0; j < 4; ++j) acc[i][j] = (floatx4){0.f,0.f,0.f,0.f};
  const size_t cb = (size_t)g * C_;
  mfma_tile_gemm(qp + (cb + tt0) * M_, M_, kp + (cb + tp0) * M_, M_, M_,
                 smem, smem + 8192, acc);
  const int lane = tid & 63, wave = tid >> 6;
  const int wm = wave >> 1, wn = wave & 1, q = lane >> 4, ln = lane & 15;
  #pragma unroll
  for (int i = 0; i < 4; ++i) {
    int rl = tt0 + wm * 64 + i * 16 + q * 4;
    #pragma unroll
    for (int j = 0; j < 4; ++j) {
      int cl = tp0 + wn * 64 + j * 16 + ln;
      #pragma unroll
      for (int r = 0; r < 4; ++r) {
        short bv = (cl <= rl + r) ? f2b(acc[i][j][r]) : (short)0;
        Ag[(size_t)(rl + r) * C_ + cl] = bv;
      }
    }
  }
}

// ---- K7: den[row] = qp.z_prefix + rowsum(Amat) + eps --------------------
__global__ __launch_bounds__(256) void den_kernel(
    const short* __restrict__ qp, const float* __restrict__ z,
    const short* __restrict__ Am, float* __restrict__ den)
{
  int wid  = blockIdx.x * 4 + (threadIdx.x >> 6);
  int lane = threadIdx.x & 63;
  int g = wid >> 8, tl = wid & 255;
  short8 qv = *(const short8*)(qp + (size_t)wid * M_ + lane * 8);
  const float* zp = z + (size_t)g * M_ + lane * 8;
  float4 z1 = *(const float4*)(zp);
  float4 z2 = *(const float4*)(zp + 4);
  float s = 0.f;
  s = fmaf(b2f(qv[0]), z1.x, s); s = fmaf(b2f(qv[1]), z1.y, s);
  s = fmaf(b2f(qv[2]), z1.z, s); s = fmaf(b2f(qv[3]), z1.w, s);
  s = fmaf(b2f(qv[4]), z2.x, s); s = fmaf(b2f(qv[5]), z2.y, s);
  s = fmaf(b2f(qv[6]), z2.z, s); s = fmaf(b2f(qv[7]), z2.w, s);
  short4v av = *(const short4v*)(Am + (size_t)g * (C_*C_) + (size_t)tl * C_ + lane * 4);
  s += b2f(av.x) + b2f(av.y) + b2f(av.z) + b2f(av.w);
  #pragma unroll
  for (int off = 32; off > 0; off >>= 1) s += __shfl_down(s, off);
  if (lane == 0) den[wid] = s + EPS_;
}

// ---- K8: out = (qp@Pb^T + Amat@vT^T) / den ------------------------------
__global__ __launch_bounds__(256) void out_mfma_kernel(
    const short* __restrict__ qp, const short* __restrict__ Pb,
    const short* __restrict__ Am, const short* __restrict__ vT,
    const float* __restrict__ den, float* __restrict__ out)
{
  __shared__ short smem[16384];
  const int g = blockIdx.z;
  const int tt0 = blockIdx.y * 128, d0 = blockIdx.x * 128;
  floatx4 acc[4][4];
  #pragma unroll
  for (int i = 0; i < 4; ++i)
    #pragma unroll
    for (int j = 0; j < 4; ++j) acc[i][j] = (floatx4){0.f,0.f,0.f,0.f};
  mfma_tile_gemm(qp + ((size_t)g * C_ + tt0) * M_, M_,
                 Pb + (size_t)g * (D_*M_) + (size_t)d0 * M_, M_, M_,
                 smem, smem + 8192, acc);
  mfma_tile_gemm(Am + ((size_t)g * C_ + tt0) * C_, C_,
                 vT + (size_t)g * (D_*C_) + (size_t)d0 * C_, C_, C_,
                 smem, smem + 8192, acc);
  const int tid = threadIdx.x, lane = tid & 63, wave = tid >> 6;
  const int wm = wave >> 1, wn = wave & 1, q = lane >> 4, ln = lane & 15;
  #pragma unroll
  for (int i = 0; i < 4; ++i) {
    int rl = tt0 + wm * 64 + i * 16 + q * 4;
    #pragma unroll
    for (int r = 0; r < 4; ++r) {
      int grow = g * C_ + rl + r;
      float rc = 1.0f / den[grow];
      #pragma unroll
      for (int j = 0; j < 4; ++j) {
        int cl = d0 + wn * 64 + j * 16 + ln;
        out[(size_t)grow * D_ + cl] = acc[i][j][r] * rc;
      }
    }
  }
}

// ---- host-side launch ---------------------------------------------------
extern "C" void kernel_launch(void* const* d_in, const int* in_sizes, int n_in,
                              void* d_out, int out_size, void* d_ws, size_t ws_size,
                              hipStream_t stream) {
  const float* q = (const float*)d_in[0];
  const float* k = (const float*)d_in[1];
  const float* v = (const float*)d_in[2];
  const float* W = (const float*)d_in[3];
  float* out = (float*)d_out;
  char* ws = (char*)d_ws;

  float* S   = (float*)(ws + OFF_S);
  short* Wt  = (short*)(ws + OFF_WT);
  short* qp  = (short*)(ws + OFF_QP);
  short* kp  = (short*)(ws + OFF_KP);
  short* kpT = (short*)(ws + OFF_KPT);
  short* vT  = (short*)(ws + OFF_VT);
  short* Am  = (short*)(ws + OFF_AM);
  float* ZP  = (float*)(ws + OFF_ZP);
  short* Pb  = (short*)(ws + OFF_PB);
  float* z   = (float*)(ws + OFF_Z);
  float* den = (float*)(ws + OFF_DEN);

  // v [g][t][d] -> vT [g][d][t]  (z<64)  and  W [k][n] -> Wt [n][k] (z==64)
  transpose_cvt_kernel<<<dim3(8, 4, NG_ + 1), 256, 0, stream>>>(v, W, vT, Wt);
  // q-phi (z=0) and k-phi (z=1, also emits kpT)
  phi_mfma_kernel<<<dim3(M_/128, (B_*L_)/128, 2), 256, 0, stream>>>(q, k, Wt, qp, kp, kpT);
  chunkstate_mfma_kernel<<<dim3(M_/128, D_/128, NG_), 256, 0, stream>>>(vT, kpT, S);
  // z partials (ZP aliases Am; prefixz consumes before qk writes Am)
  zsum_part_kernel<<<dim3(2, 4, NG_), 256, 0, stream>>>(kp, ZP);
  prefixz_kernel<<<8, 256, 0, stream>>>(ZP, z);
  prefixS_kernel<<<(B_*D_*M_)/256, 256, 0, stream>>>(S, Pb);
  qk_mfma_kernel<<<dim3(C_/128, C_/128, NG_), 256, 0, stream>>>(qp, kp, Am);
  den_kernel<<<(B_*L_)/4, 256, 0, stream>>>(qp, z, Am, den);
  out_mfma_kernel<<<dim3(D_/128, C_/128, NG_), 256, 0, stream>>>(qp, Pb, Am, vT, den, out);
}

// Round 6
// 198.415 us; speedup vs baseline: 1.5503x; 1.0679x over previous
//
#include <hip/hip_runtime.h>

// ---- problem constants --------------------------------------------------
#define B_ 4
#define L_ 4096
#define D_ 256
#define M_ 512
#define C_ 256
#define NC_ 16
#define NG_ (B_*NC_)
#define EPS_ 1e-6f
#define RSQRT_D_ 0.0625f
#define RSQRT_M_ 0.044194173824159216f

typedef __attribute__((ext_vector_type(8))) short short8;
typedef __attribute__((ext_vector_type(4))) short short4v;
typedef __attribute__((ext_vector_type(4))) float floatx4;

// ---- bf16 helpers (RNE) -------------------------------------------------
__device__ __forceinline__ short f2b(float f) {
  union { float f; unsigned u; } c; c.f = f;
  unsigned r = c.u + 0x7fffu + ((c.u >> 16) & 1u);
  return (short)(r >> 16);
}
__device__ __forceinline__ float b2f(short s) {
  union { unsigned u; float f; } c; c.u = ((unsigned)(unsigned short)s) << 16;
  return c.f;
}

// ---- workspace layout (byte offsets) ------------------------------------
#define OFF_S    0u                 // fp32 [64][256 d][512 m]; Wt aliases head
#define OFF_WT   0u                 // bf16 [512 n][256 k] (dead before chunkstate)
#define OFF_QP   33554432u          // bf16 [16384][512]
#define OFF_KP   50331648u          // bf16 [16384][512]
#define OFF_KPT  67108864u          // bf16 [64][512][256]
#define OFF_VT   83886080u          // bf16 [64][256][256]
#define OFF_AM   92274688u          // bf16 [64][256][256]
#define OFF_ZP   92274688u          // fp32 [64][4][512] z-partials; ALIASES Am,
                                    //   consumed by prefixz BEFORE qk writes Am
#define OFF_PB   100663296u         // bf16 [64][256][512]
#define OFF_Z    117440512u         // fp32 [64][512]
#define OFF_DEN  117571584u         // fp32 [16384]

// ======================================================================
// MFMA GEMM core with register double-buffered staging.
// C[128x128] += A[128xK] * B[128xK]^T; A,B row-major bf16 [row][k].
// 256 threads = 4 waves (2x2), BK=64. Coalesced 16B global loads ->
// XOR-swizzled ds_write_b128 -> conflict-free ds_read_b128 fragments.
// Next iter's global loads issue BEFORE the barrier so they fly during
// barrier-wait + MFMA (vmcnt waits land at the next ds_write).
// ======================================================================
__device__ __forceinline__ void mfma_tile_gemm(
    const short* __restrict__ Ag, int lda,
    const short* __restrict__ Bg, int ldb,
    int K, short* sA, short* sB, floatx4 acc[4][4])
{
  const int tid  = threadIdx.x;
  const int lane = tid & 63;
  const int wave = tid >> 6;
  const int wm = wave >> 1, wn = wave & 1;
  const int q = lane >> 4, ml = lane & 15;

  short8 pa[4], pb[4];
  #pragma unroll
  for (int it = 0; it < 4; ++it) {
    int ci = tid + 256 * it;
    int m = ci >> 3, k8 = ci & 7;
    pa[it] = *(const short8*)(Ag + (size_t)m * lda + k8 * 8);
    pb[it] = *(const short8*)(Bg + (size_t)m * ldb + k8 * 8);
  }
  for (int k0 = 0; k0 < K; k0 += 64) {
    #pragma unroll
    for (int it = 0; it < 4; ++it) {
      int ci = tid + 256 * it;
      int m = ci >> 3, k8 = ci & 7;
      int dst = (k8 >> 2) * 512 + (m >> 4) * 64 + (k8 & 3) * 16 + ((m & 15) ^ k8);
      *(short8*)(sA + dst * 8) = pa[it];
      *(short8*)(sB + dst * 8) = pb[it];
    }
    if (k0 + 64 < K) {      // prefetch next slice before the barrier
      #pragma unroll
      for (int it = 0; it < 4; ++it) {
        int ci = tid + 256 * it;
        int m = ci >> 3, k8 = ci & 7;
        pa[it] = *(const short8*)(Ag + (size_t)m * lda + k0 + 64 + k8 * 8);
        pb[it] = *(const short8*)(Bg + (size_t)m * ldb + k0 + 64 + k8 * 8);
      }
    }
    __syncthreads();
    #pragma unroll
    for (int ks = 0; ks < 2; ++ks) {
      short8 a[4], b[4];
      int k8 = ks * 4 + q;
      #pragma unroll
      for (int i = 0; i < 4; ++i) {
        int ca = ks * 512 + (wm * 4 + i) * 64 + q * 16 + (ml ^ k8);
        a[i] = *(const short8*)(sA + ca * 8);
        int cb = ks * 512 + (wn * 4 + i) * 64 + q * 16 + (ml ^ k8);
        b[i] = *(const short8*)(sB + cb * 8);
      }
      #pragma unroll
      for (int i = 0; i < 4; ++i)
        #pragma unroll
        for (int j = 0; j < 4; ++j)
          acc[i][j] = __builtin_amdgcn_mfma_f32_16x16x32_bf16(a[i], b[j], acc[i][j], 0, 0, 0);
    }
    __syncthreads();
  }
}

// ---- K1: combined transpose+cvt: v (z<NG_) and W (z==NG_) ---------------
__global__ __launch_bounds__(256) void transpose_cvt_kernel(
    const float* __restrict__ v, const float* __restrict__ W,
    short* __restrict__ vT, short* __restrict__ Wt)
{
  const int z = blockIdx.z;
  const float* src; short* dst; int ld_in, ld_out;
  if (z < NG_) {
    if (blockIdx.x >= 4) return;     // v uses 4x4 tiles; W grid x is 8-wide
    src = v + (size_t)z * (C_*D_) + (size_t)blockIdx.y * 64 * D_ + blockIdx.x * 64;
    dst = vT + (size_t)z * (D_*C_) + (size_t)blockIdx.x * 64 * C_ + blockIdx.y * 64;
    ld_in = D_; ld_out = C_;
  } else {
    src = W + (size_t)blockIdx.y * 64 * M_ + blockIdx.x * 64;
    dst = Wt + (size_t)blockIdx.x * 64 * D_ + blockIdx.y * 64;
    ld_in = M_; ld_out = D_;
  }
  __shared__ short sm[64 * 65];
  const int tid = threadIdx.x;
  #pragma unroll
  for (int it = 0; it < 4; ++it) {
    int ci = tid + 256 * it;
    int row = ci >> 4, c4 = ci & 15;
    float4 x = *(const float4*)(src + (size_t)row * ld_in + c4 * 4);
    sm[(c4 * 4 + 0) * 65 + row] = f2b(x.x);
    sm[(c4 * 4 + 1) * 65 + row] = f2b(x.y);
    sm[(c4 * 4 + 2) * 65 + row] = f2b(x.z);
    sm[(c4 * 4 + 3) * 65 + row] = f2b(x.w);
  }
  __syncthreads();
  #pragma unroll
  for (int it = 0; it < 2; ++it) {
    int ci = tid + 256 * it;
    int dr = ci >> 3, t8 = ci & 7;
    short8 o;
    #pragma unroll
    for (int u = 0; u < 8; ++u) o[u] = sm[dr * 65 + t8 * 8 + u];
    *(short8*)(dst + (size_t)dr * ld_out + t8 * 8) = o;
  }
}

// ---- K2: merged q/k phi = exp(X@W/sqrt(d) - 0.5||x||^2)/sqrt(M) ---------
// blockIdx.z: 0 -> q, 1 -> k (also writes kpT). Register double-buffered
// staging: fp32 A + bf16 Wt prefetched one K-slice ahead.
__global__ __launch_bounds__(256) void phi_mfma_kernel(
    const float* __restrict__ qin, const float* __restrict__ kin,
    const short* __restrict__ Wt,
    short* __restrict__ qp, short* __restrict__ kp, short* __restrict__ kpT)
{
  const bool is_k = (blockIdx.z == 1);
  const float* X = is_k ? kin : qin;
  short* outP = is_k ? kp : qp;
  __shared__ short smem[17664];   // sA 8192 | sB 8192 | tbuf overlaps | sqs @17408
  short* sA = smem;
  short* sB = smem + 8192;
  float* sqs = (float*)(smem + 17408);
  const int row0 = blockIdx.y * 128, col0 = blockIdx.x * 128;
  const int tid = threadIdx.x, lane = tid & 63, wave = tid >> 6;
  const int wm = wave >> 1, wn = wave & 1, q = lane >> 4, ml = lane & 15;
  floatx4 acc[4][4];
  #pragma unroll
  for (int i = 0; i < 4; ++i)
    #pragma unroll
    for (int j = 0; j < 4; ++j) acc[i][j] = (floatx4){0.f,0.f,0.f,0.f};

  float4 px0[4], px1[4];
  short8 pwb[4];
  #pragma unroll
  for (int it = 0; it < 4; ++it) {
    int ci = tid + 256 * it;
    int m = ci >> 3, c = ci & 7;
    const float* src = X + (size_t)(row0 + m) * D_ + c * 8;
    px0[it] = *(const float4*)src;
    px1[it] = *(const float4*)(src + 4);
    pwb[it] = *(const short8*)(Wt + (size_t)(col0 + m) * D_ + c * 8);
  }
  float ssq[4] = {0.f, 0.f, 0.f, 0.f};
  for (int k0 = 0; k0 < D_; k0 += 64) {
    #pragma unroll
    for (int it = 0; it < 4; ++it) {
      int ci = tid + 256 * it;
      int m = ci >> 3, c = ci & 7;
      float4 x0 = px0[it], x1 = px1[it];
      short8 vv;
      vv[0] = f2b(x0.x); vv[1] = f2b(x0.y); vv[2] = f2b(x0.z); vv[3] = f2b(x0.w);
      vv[4] = f2b(x1.x); vv[5] = f2b(x1.y); vv[6] = f2b(x1.z); vv[7] = f2b(x1.w);
      ssq[it] += x0.x*x0.x + x0.y*x0.y + x0.z*x0.z + x0.w*x0.w
               + x1.x*x1.x + x1.y*x1.y + x1.z*x1.z + x1.w*x1.w;
      *(short8*)(sA + (c * 128 + (m ^ c)) * 8) = vv;
      *(short8*)(sB + (c * 128 + (m ^ c)) * 8) = pwb[it];
    }
    if (k0 + 64 < D_) {     // prefetch next slice before the barrier
      #pragma unroll
      for (int it = 0; it < 4; ++it) {
        int ci = tid + 256 * it;
        int m = ci >> 3, c = ci & 7;
        const float* src = X + (size_t)(row0 + m) * D_ + k0 + 64 + c * 8;
        px0[it] = *(const float4*)src;
        px1[it] = *(const float4*)(src + 4);
        pwb[it] = *(const short8*)(Wt + (size_t)(col0 + m) * D_ + k0 + 64 + c * 8);
      }
    }
    __syncthreads();
    #pragma unroll
    for (int ks = 0; ks < 2; ++ks) {
      short8 a[4], b[4];
      int c = ks * 4 + q;
      #pragma unroll
      for (int i = 0; i < 4; ++i) {
        int ra = (wm * 64 + i * 16 + ml) ^ c;
        a[i] = *(const short8*)(sA + (c * 128 + ra) * 8);
        int rb = (wn * 64 + i * 16 + ml) ^ c;
        b[i] = *(const short8*)(sB + (c * 128 + rb) * 8);
      }
      #pragma unroll
      for (int i = 0; i < 4; ++i)
        #pragma unroll
        for (int j = 0; j < 4; ++j)
          acc[i][j] = __builtin_amdgcn_mfma_f32_16x16x32_bf16(a[i], b[j], acc[i][j], 0, 0, 0);
    }
    __syncthreads();
  }
  // reduce ssq across the 8 threads sharing tid>>3 (consecutive lanes)
  #pragma unroll
  for (int o = 1; o < 8; o <<= 1)
    #pragma unroll
    for (int it = 0; it < 4; ++it) ssq[it] += __shfl_xor(ssq[it], o);
  if ((tid & 7) == 0) {
    #pragma unroll
    for (int it = 0; it < 4; ++it) sqs[(tid >> 3) + 32 * it] = 0.5f * ssq[it];
  }
  __syncthreads();
  // epilogue
  #pragma unroll
  for (int i = 0; i < 4; ++i) {
    int rl = wm * 64 + i * 16 + q * 4;
    float sqv[4];
    #pragma unroll
    for (int r = 0; r < 4; ++r) sqv[r] = sqs[rl + r];
    #pragma unroll
    for (int j = 0; j < 4; ++j) {
      int cl = wn * 64 + j * 16 + ml;
      short4v tb;
      #pragma unroll
      for (int r = 0; r < 4; ++r) {
        float pv = __expf(fmaf(acc[i][j][r], RSQRT_D_, -sqv[r])) * RSQRT_M_;
        short bv = f2b(pv);
        outP[(size_t)(row0 + rl + r) * M_ + col0 + cl] = bv;
        tb[r] = bv;
      }
      if (is_k)   // col-major LDS [col][row+pad8] for transposed write
        *(short4v*)(smem + (size_t)cl * 136 + rl) = tb;
    }
  }
  if (is_k) {
    __syncthreads();
    int g = row0 >> 8, tb0 = row0 & 255;
    #pragma unroll
    for (int it = 0; it < 8; ++it) {
      int ci = tid + 256 * it;
      int t8 = ci & 15, cc = ci >> 4;
      short8 vv = *(const short8*)(smem + (size_t)cc * 136 + t8 * 8);
      *(short8*)(kpT + (size_t)g * (M_*C_) + (size_t)(col0 + cc) * C_ + tb0 + t8 * 8) = vv;
    }
  }
}

// ---- K3: S[g][d][m] = sum_t vT[g][d][t]*kpT[g][m][t], fp32 out ----------
__global__ __launch_bounds__(256) void chunkstate_mfma_kernel(
    const short* __restrict__ vT, const short* __restrict__ kpT,
    float* __restrict__ S)
{
  __shared__ short smem[16384];
  const int g = blockIdx.z, d0 = blockIdx.y * 128, m0 = blockIdx.x * 128;
  floatx4 acc[4][4];
  #pragma unroll
  for (int i = 0; i < 4; ++i)
    #pragma unroll
    for (int j = 0; j < 4; ++j) acc[i][j] = (floatx4){0.f,0.f,0.f,0.f};
  mfma_tile_gemm(vT + (size_t)g * (D_*C_) + (size_t)d0 * C_, C_,
                 kpT + (size_t)g * (M_*C_) + (size_t)m0 * C_, C_, C_,
                 smem, smem + 8192, acc);
  const int tid = threadIdx.x, lane = tid & 63, wave = tid >> 6;
  const int wm = wave >> 1, wn = wave & 1, q = lane >> 4, ln = lane & 15;
  #pragma unroll
  for (int i = 0; i < 4; ++i) {
    int rl = d0 + wm * 64 + i * 16 + q * 4;
    #pragma unroll
    for (int j = 0; j < 4; ++j) {
      int cl = m0 + wn * 64 + j * 16 + ln;
      #pragma unroll
      for (int r = 0; r < 4; ++r)
        S[((size_t)g * D_ + rl + r) * M_ + cl] = acc[i][j][r];
    }
  }
}

// ---- K4a: z partials: ZP[g][p][m] = sum of 64 rows of kp chunk ----------
__global__ __launch_bounds__(256) void zsum_part_kernel(
    const short* __restrict__ kp, float* __restrict__ ZP)
{
  const int mb = blockIdx.x, p = blockIdx.y, g = blockIdx.z;
  const int m = mb * 256 + threadIdx.x;
  const short* base = kp + ((size_t)g * C_ + p * 64) * M_ + m;
  float s = 0.f;
  #pragma unroll 8
  for (int t = 0; t < 64; ++t) s += b2f(base[(size_t)t * M_]);
  ZP[((size_t)g * 4 + p) * M_ + m] = s;
}

// ---- K4b: z[b][i][m] = exclusive chunk prefix of folded partials --------
__global__ __launch_bounds__(256) void prefixz_kernel(
    const float* __restrict__ ZP, float* __restrict__ z)
{
  int j = blockIdx.x * 256 + threadIdx.x;   // 0..2047
  int b = j >> 9, m = j & 511;
  float run = 0.f;
  for (int i = 0; i < NC_; ++i) {
    int g = b * NC_ + i;
    z[(size_t)g * M_ + m] = run;
    const float* zp = ZP + (size_t)g * 4 * M_ + m;
    run += zp[0] + zp[M_] + zp[2*M_] + zp[3*M_];
  }
}

// ---- K5: exclusive chunk prefix of S (fp32 in) -> Pb (bf16 out) ---------
__global__ __launch_bounds__(256) void prefixS_kernel(
    const float* __restrict__ S, short* __restrict__ Pb)
{
  int j = blockIdx.x * 256 + threadIdx.x;   // 524288
  int b = j >> 17, e = j & 131071;
  float run = 0.f;
  size_t idx = ((size_t)b * NC_) * 131072 + e;
  for (int i = 0; i < NC_; ++i) {
    float t = S[idx];
    Pb[idx] = f2b(run);
    run += t;
    idx += 131072;
  }
}

// ---- K6: Amat[g][t][t'] = masked qp.kp^T, bf16 out ----------------------
__global__ __launch_bounds__(256) void qk_mfma_kernel(
    const short* __restrict__ qp, const short* __restrict__ kp,
    short* __restrict__ Am)
{
  const int g = blockIdx.z;
  const int tt0 = blockIdx.y * 128, tp0 = blockIdx.x * 128;
  short* Ag = Am + (size_t)g * (C_*C_);
  const int tid = threadIdx.x;
  if (tp0 > tt0) {
    short8 z8 = 0;
    #pragma unroll
    for (int it = 0; it < 8; ++it) {
      int ci = tid + 256 * it;
      int row = ci >> 4, c8 = ci & 15;
      *(short8*)(Ag + (size_t)(tt0 + row) * C_ + tp0 + c8 * 8) = z8;
    }
    return;
  }
  __shared__ short smem[16384];
  floatx4 acc[4][4];
  #pragma unroll
  for (int i = 0; i < 4; ++i)
    #pragma unroll
    for (int j = 0; j < 4; ++j) acc[i][j] = (floatx4){0.f,0.f,0.f,0.f};
  const size_t cb = (size_t)g * C_;
  mfma_tile_gemm(qp + (cb + tt0) * M_, M_, kp + (cb + tp0) * M_, M_, M_,
                 smem, smem + 8192, acc);
  const int lane = tid & 63, wave = tid >> 6;
  const int wm = wave >> 1, wn = wave & 1, q = lane >> 4, ln = lane & 15;
  #pragma unroll
  for (int i = 0; i < 4; ++i) {
    int rl = tt0 + wm * 64 + i * 16 + q * 4;
    #pragma unroll
    for (int j = 0; j < 4; ++j) {
      int cl = tp0 + wn * 64 + j * 16 + ln;
      #pragma unroll
      for (int r = 0; r < 4; ++r) {
        short bv = (cl <= rl + r) ? f2b(acc[i][j][r]) : (short)0;
        Ag[(size_t)(rl + r) * C_ + cl] = bv;
      }
    }
  }
}

// ---- K7: den[row] = qp.z_prefix + rowsum(Amat) + eps --------------------
__global__ __launch_bounds__(256) void den_kernel(
    const short* __restrict__ qp, const float* __restrict__ z,
    const short* __restrict__ Am, float* __restrict__ den)
{
  int wid  = blockIdx.x * 4 + (threadIdx.x >> 6);
  int lane = threadIdx.x & 63;
  int g = wid >> 8, tl = wid & 255;
  short8 qv = *(const short8*)(qp + (size_t)wid * M_ + lane * 8);
  const float* zp = z + (size_t)g * M_ + lane * 8;
  float4 z1 = *(const float4*)(zp);
  float4 z2 = *(const float4*)(zp + 4);
  float s = 0.f;
  s = fmaf(b2f(qv[0]), z1.x, s); s = fmaf(b2f(qv[1]), z1.y, s);
  s = fmaf(b2f(qv[2]), z1.z, s); s = fmaf(b2f(qv[3]), z1.w, s);
  s = fmaf(b2f(qv[4]), z2.x, s); s = fmaf(b2f(qv[5]), z2.y, s);
  s = fmaf(b2f(qv[6]), z2.z, s); s = fmaf(b2f(qv[7]), z2.w, s);
  short4v av = *(const short4v*)(Am + (size_t)g * (C_*C_) + (size_t)tl * C_ + lane * 4);
  s += b2f(av.x) + b2f(av.y) + b2f(av.z) + b2f(av.w);
  #pragma unroll
  for (int off = 32; off > 0; off >>= 1) s += __shfl_down(s, off);
  if (lane == 0) den[wid] = s + EPS_;
}

// ---- K8: out = (qp@Pb^T + Amat@vT^T) / den ------------------------------
__global__ __launch_bounds__(256) void out_mfma_kernel(
    const short* __restrict__ qp, const short* __restrict__ Pb,
    const short* __restrict__ Am, const short* __restrict__ vT,
    const float* __restrict__ den, float* __restrict__ out)
{
  __shared__ short smem[16384];
  const int g = blockIdx.z;
  const int tt0 = blockIdx.y * 128, d0 = blockIdx.x * 128;
  floatx4 acc[4][4];
  #pragma unroll
  for (int i = 0; i < 4; ++i)
    #pragma unroll
    for (int j = 0; j < 4; ++j) acc[i][j] = (floatx4){0.f,0.f,0.f,0.f};
  mfma_tile_gemm(qp + ((size_t)g * C_ + tt0) * M_, M_,
                 Pb + (size_t)g * (D_*M_) + (size_t)d0 * M_, M_, M_,
                 smem, smem + 8192, acc);
  mfma_tile_gemm(Am + ((size_t)g * C_ + tt0) * C_, C_,
                 vT + (size_t)g * (D_*C_) + (size_t)d0 * C_, C_, C_,
                 smem, smem + 8192, acc);
  const int tid = threadIdx.x, lane = tid & 63, wave = tid >> 6;
  const int wm = wave >> 1, wn = wave & 1, q = lane >> 4, ln = lane & 15;
  #pragma unroll
  for (int i = 0; i < 4; ++i) {
    int rl = tt0 + wm * 64 + i * 16 + q * 4;
    #pragma unroll
    for (int r = 0; r < 4; ++r) {
      int grow = g * C_ + rl + r;
      float rc = 1.0f / den[grow];
      #pragma unroll
      for (int j = 0; j < 4; ++j) {
        int cl = d0 + wn * 64 + j * 16 + ln;
        out[(size_t)grow * D_ + cl] = acc[i][j][r] * rc;
      }
    }
  }
}

// ---- host-side launch ---------------------------------------------------
extern "C" void kernel_launch(void* const* d_in, const int* in_sizes, int n_in,
                              void* d_out, int out_size, void* d_ws, size_t ws_size,
                              hipStream_t stream) {
  const float* q = (const float*)d_in[0];
  const float* k = (const float*)d_in[1];
  const float* v = (const float*)d_in[2];
  const float* W = (const float*)d_in[3];
  float* out = (float*)d_out;
  char* ws = (char*)d_ws;

  float* S   = (float*)(ws + OFF_S);
  short* Wt  = (short*)(ws + OFF_WT);
  short* qp  = (short*)(ws + OFF_QP);
  short* kp  = (short*)(ws + OFF_KP);
  short* kpT = (short*)(ws + OFF_KPT);
  short* vT  = (short*)(ws + OFF_VT);
  short* Am  = (short*)(ws + OFF_AM);
  float* ZP  = (float*)(ws + OFF_ZP);
  short* Pb  = (short*)(ws + OFF_PB);
  float* z   = (float*)(ws + OFF_Z);
  float* den = (float*)(ws + OFF_DEN);

  // v [g][t][d] -> vT [g][d][t]  (z<64)  and  W [k][n] -> Wt [n][k] (z==64)
  transpose_cvt_kernel<<<dim3(8, 4, NG_ + 1), 256, 0, stream>>>(v, W, vT, Wt);
  // q-phi (z=0) and k-phi (z=1, also emits kpT)
  phi_mfma_kernel<<<dim3(M_/128, (B_*L_)/128, 2), 256, 0, stream>>>(q, k, Wt, qp, kp, kpT);
  chunkstate_mfma_kernel<<<dim3(M_/128, D_/128, NG_), 256, 0, stream>>>(vT, kpT, S);
  // z partials (ZP aliases Am; prefixz consumes before qk writes Am)
  zsum_part_kernel<<<dim3(2, 4, NG_), 256, 0, stream>>>(kp, ZP);
  prefixz_kernel<<<8, 256, 0, stream>>>(ZP, z);
  prefixS_kernel<<<(B_*D_*M_)/256, 256, 0, stream>>>(S, Pb);
  qk_mfma_kernel<<<dim3(C_/128, C_/128, NG_), 256, 0, stream>>>(qp, kp, Am);
  den_kernel<<<(B_*L_)/4, 256, 0, stream>>>(qp, z, Am, den);
  out_mfma_kernel<<<dim3(D_/128, C_/128, NG_), 256, 0, stream>>>(qp, Pb, Am, vT, den, out);
}